// Round 16
// baseline (160.999 us; speedup 1.0000x reference)
//
#include <hip/hip_runtime.h>
#include <cstdint>
#include <cstddef>

#define D 64
#define D_FEAT 128
#define SLOPE 0.01f
#define BSH 7                 // bucket = dst >> 7  (128 nodes per bucket)
#define BW 128
#define CAP 2560              // per-bucket slot capacity (mean 2046, +11 sigma)
#define WS 72                 // LDS weight row stride (bf16): 144B, 16B-aligned, 2-way banks
#define GST 16                // gcur stride (ints): one counter per 64B line
#define NID 128               // id-conversion blocks inside partmlp

typedef __attribute__((ext_vector_type(8))) short bf16x8;
typedef __attribute__((ext_vector_type(4))) float f32x4;
typedef __attribute__((ext_vector_type(2))) float f32x2;

struct P7 { const float* w[7]; };

__device__ __forceinline__ float leaky(float v) { return v >= 0.f ? v : SLOPE * v; }

__device__ __forceinline__ unsigned short f2bf(float f) {
    union { float f; unsigned u; } v; v.f = f;
    unsigned r = v.u + 0x7FFF + ((v.u >> 16) & 1);   // RNE
    return (unsigned short)(r >> 16);
}
__device__ __forceinline__ float bflo(unsigned u) {
    union { unsigned x; float f; } v; v.x = u << 16; return v.f;
}
__device__ __forceinline__ float bfhi(unsigned u) {
    union { unsigned x; float f; } v; v.x = u & 0xFFFF0000u; return v.f;
}
// one-instruction packed f32->2xbf16 (RNE); no builtin on gfx950
__device__ __forceinline__ unsigned pk_bf16(float lo, float hi) {
    unsigned r;
    asm("v_cvt_pk_bf16_f32 %0, %1, %2" : "=v"(r) : "v"(lo), "v"(hi));
    return r;
}

// ---------------- prep: weights fp32 row-major -> bf16 col-major; + gcur init --
__global__ __launch_bounds__(256) void k_prep(P7 p, unsigned short* __restrict__ out,
    int* __restrict__ gcur, int nbk)
{
    int m = blockIdx.x;
    if (m == 7) {
        for (int i = threadIdx.x; i < nbk; i += 256) gcur[i * GST] = i * CAP;
        return;
    }
    int K = (m == 0) ? 128 : 64;
    const float* W = p.w[m];
    unsigned short* o = out + ((m == 0) ? 0 : 8192 + (m - 1) * 4096);
    int total = K * 64;
    for (int i = threadIdx.x; i < total; i += 256) {
        int col = i / K, k = i - col * K;
        o[i] = f2bf(W[k * 64 + col]);     // o[col*K + k]
    }
}

// ---------------- fused: partition | MLP | id->bf16 (3 block ranges) ----------
__global__ __launch_bounds__(256) void k_partmlp(
    const int* __restrict__ esrc, const int* __restrict__ edst,
    int* __restrict__ gcur, unsigned* __restrict__ pairs, int E, int nPart,
    const float* __restrict__ F, const unsigned short* __restrict__ Wt,
    const float* __restrict__ bm,
    unsigned short* __restrict__ Xb, unsigned char* __restrict__ Xf8,
    const float* __restrict__ IDf, unsigned short* __restrict__ IDb, int N)
{
    __shared__ int lcnt[1024];
    __shared__ int lbase[1024];
    if ((int)blockIdx.x < nPart) {
        // ---- partition branch: single-pass, 4096 edges/block ----
        int base = blockIdx.x * 4096;
        for (int i = threadIdx.x; i < 1024; i += 256) lcnt[i] = 0;
        __syncthreads();
        int dv[16], rv[16];
#pragma unroll
        for (int i = 0; i < 16; ++i) {
            int e = base + i * 256 + threadIdx.x;
            if (e < E) {
                dv[i] = edst[e];
                rv[i] = atomicAdd(&lcnt[dv[i] >> BSH], 1);
            } else dv[i] = -1;
        }
        __syncthreads();
        for (int i = threadIdx.x; i < 1024; i += 256) {
            int c = lcnt[i];
            lbase[i] = c ? atomicAdd(&gcur[i * GST], c) : 0;   // line-padded counters
        }
        __syncthreads();
#pragma unroll
        for (int i = 0; i < 16; ++i) {
            if (dv[i] >= 0) {
                int e = base + i * 256 + threadIdx.x;
                unsigned pk = ((unsigned)(dv[i] & (BW - 1)) << 25) | (unsigned)esrc[e];
                pairs[lbase[dv[i] >> BSH] + rv[i]] = pk;
            }
        }
        return;
    }
    if ((int)blockIdx.x >= nPart + 512) {
        // ---- id_embedding fp32 -> bf16 branch (optional) ----
        if (!IDb) return;
        int cid = blockIdx.x - nPart - 512;
        int ngrp = N * 8;            // groups of 8 elements
        const float4* src4 = (const float4*)IDf;
        uint4* dst4 = (uint4*)IDb;
        for (int i = cid * 256 + threadIdx.x; i < ngrp; i += NID * 256) {
            float4 a = src4[i * 2], b = src4[i * 2 + 1];
            uint4 o;
            o.x = pk_bf16(a.x, a.y);
            o.y = pk_bf16(a.z, a.w);
            o.z = pk_bf16(b.x, b.y);
            o.w = pk_bf16(b.z, b.w);
            dst4[i] = o;
        }
        return;
    }
    // ---- MLP branch: x = L2norm(F@Wm + bm) -> bf16 + fp8 ----
    int lane = threadIdx.x & 63, w = threadIdx.x >> 6;
    int cl = lane & 15, g = lane >> 4;
    int ntiles = (N + 63) / 64;
    int tb0 = blockIdx.x - nPart;
    int step = 512;

    bf16x8 Wmf[4][4];
#pragma unroll
    for (int ks = 0; ks < 4; ++ks)
#pragma unroll
        for (int nt = 0; nt < 4; ++nt)
            Wmf[ks][nt] = *(const bf16x8*)(Wt + (nt * 16 + cl) * 128 + ks * 32 + g * 8);
    float bmv[4];
#pragma unroll
    for (int nt = 0; nt < 4; ++nt) bmv[nt] = bm[nt * 16 + cl];

    for (int tb = tb0; tb < ntiles; tb += step) {
        int node0 = tb * 64 + w * 16;
        if (node0 >= N) continue;
        f32x4 acc[4];
#pragma unroll
        for (int nt = 0; nt < 4; ++nt) acc[nt] = (f32x4){0.f, 0.f, 0.f, 0.f};
#pragma unroll
        for (int ks = 0; ks < 4; ++ks) {
            const float4* fp = (const float4*)(F + (size_t)(node0 + cl) * D_FEAT + ks * 32 + g * 8);
            float4 a = fp[0], b = fp[1];
            bf16x8 af;
            af[0] = (short)f2bf(a.x); af[1] = (short)f2bf(a.y);
            af[2] = (short)f2bf(a.z); af[3] = (short)f2bf(a.w);
            af[4] = (short)f2bf(b.x); af[5] = (short)f2bf(b.y);
            af[6] = (short)f2bf(b.z); af[7] = (short)f2bf(b.w);
#pragma unroll
            for (int nt = 0; nt < 4; ++nt)
                acc[nt] = __builtin_amdgcn_mfma_f32_16x16x32_bf16(af, Wmf[ks][nt], acc[nt], 0, 0, 0);
        }
        float ss[4] = {0.f, 0.f, 0.f, 0.f};
#pragma unroll
        for (int nt = 0; nt < 4; ++nt)
#pragma unroll
            for (int i = 0; i < 4; ++i) {
                float v = acc[nt][i] + bmv[nt];
                acc[nt][i] = v;
                ss[i] += v * v;
            }
#pragma unroll
        for (int off = 8; off >= 1; off >>= 1)
#pragma unroll
            for (int i = 0; i < 4; ++i)
                ss[i] += __shfl_xor(ss[i], off);
        float inv[4];
#pragma unroll
        for (int i = 0; i < 4; ++i)
            inv[i] = 1.f / fmaxf(sqrtf(ss[i]), 1e-12f);
#pragma unroll
        for (int nt = 0; nt < 4; ++nt)
#pragma unroll
            for (int i = 0; i < 4; ++i) {
                float v = acc[nt][i] * inv[i];
                size_t row = (size_t)(node0 + g * 4 + i);
                Xb[row * D + nt * 16 + cl] = f2bf(v);
                int p8 = __builtin_amdgcn_cvt_pk_fp8_f32(v, v, 0, false);
                Xf8[row * D + nt * 16 + cl] = (unsigned char)(p8 & 0xFF);
            }
    }
}

// ---------------- per-bucket counting sort -> per-node ranges (coalesced) ------
__global__ __launch_bounds__(256) void k_sort(const unsigned* __restrict__ pairs,
    const int* __restrict__ gcur, int2* __restrict__ rng,
    int* __restrict__ srcs, int N)
{
    __shared__ int lh[BW];
    __shared__ int cur[BW];
    __shared__ unsigned buf[CAP];
    int b = blockIdx.x;
    int node0 = b << BSH;
    int s0 = b * CAP;
    int cnt = gcur[b * GST] - s0;
    if (threadIdx.x < BW) lh[threadIdx.x] = 0;
    __syncthreads();
    for (int i = threadIdx.x; i < cnt; i += 256)
        atomicAdd(&lh[pairs[s0 + i] >> 25], 1);
    __syncthreads();
    if (threadIdx.x < 64) {   // wave 0: exclusive scan of 128 counts, 2/lane
        int a = lh[2 * threadIdx.x], c = lh[2 * threadIdx.x + 1];
        int s = a + c, inc = s;
#pragma unroll
        for (int d = 1; d < 64; d <<= 1) {
            int u = __shfl_up(inc, d);
            if ((int)threadIdx.x >= d) inc += u;
        }
        int ex = inc - s;
        cur[2 * threadIdx.x] = ex;
        cur[2 * threadIdx.x + 1] = ex + a;
    }
    __syncthreads();
    if (threadIdx.x < BW) {
        int node = node0 + threadIdx.x;
        if (node < N)
            rng[node] = make_int2(s0 + cur[threadIdx.x],
                                  s0 + cur[threadIdx.x] + lh[threadIdx.x]);
    }
    __syncthreads();
    for (int i = threadIdx.x; i < cnt; i += 256) {
        unsigned p = pairs[s0 + i];
        int r = atomicAdd(&cur[p >> 25], 1);
        buf[r] = p & 0x1FFFFFFu;
    }
    __syncthreads();
    for (int i = threadIdx.x; i < cnt; i += 256)
        srcs[s0 + i] = (int)buf[i];
}

// ---------------- gather (fp8 rows): 8-lane group per node, no cross-group reduce
__global__ __launch_bounds__(256) void k_gather8(const int2* __restrict__ rng,
    const int* __restrict__ srcs,
    const unsigned char* __restrict__ Xf8, unsigned short* __restrict__ Ab, int N)
{
    int lane = threadIdx.x & 63, w = threadIdx.x >> 6;
    int grp = lane >> 3, li = lane & 7;     // group owns one node; li = col block
    int node = blockIdx.x * 32 + w * 8 + grp;
    if (node >= N) return;
    int2 r = rng[node];
    f32x2 acc[4];
#pragma unroll
    for (int i = 0; i < 4; ++i) acc[i] = (f32x2){0.f, 0.f};
    for (int base = r.x; base < r.y; base += 8) {
        int sidv = (base + li < r.y) ? srcs[base + li] : 0;   // 8 sids per group
        int m = r.y - base; if (m > 8) m = 8;
        for (int j = 0; j < m; ++j) {
            int s = __shfl(sidv, (grp << 3) | j);
            uint2 u = *(const uint2*)(Xf8 + (size_t)s * D + li * 8);
            acc[0] += __builtin_amdgcn_cvt_pk_f32_fp8(u.x, false);
            acc[1] += __builtin_amdgcn_cvt_pk_f32_fp8(u.x, true);
            acc[2] += __builtin_amdgcn_cvt_pk_f32_fp8(u.y, false);
            acc[3] += __builtin_amdgcn_cvt_pk_f32_fp8(u.y, true);
        }
    }
    uint4 o;
    o.x = pk_bf16(acc[0].x, acc[0].y);
    o.y = pk_bf16(acc[1].x, acc[1].y);
    o.z = pk_bf16(acc[2].x, acc[2].y);
    o.w = pk_bf16(acc[3].x, acc[3].y);
    *(uint4*)(Ab + (size_t)node * D + li * 8) = o;
}

// ---------------- gather (bf16 rows): layer 2, same group-per-node structure ---
__global__ __launch_bounds__(256) void k_gather(const int2* __restrict__ rng,
    const int* __restrict__ srcs,
    const unsigned short* __restrict__ Xb, unsigned short* __restrict__ Ab, int N)
{
    int lane = threadIdx.x & 63, w = threadIdx.x >> 6;
    int grp = lane >> 3, li = lane & 7;
    int node = blockIdx.x * 32 + w * 8 + grp;
    if (node >= N) return;
    int2 r = rng[node];
    f32x2 acc[4];
#pragma unroll
    for (int i = 0; i < 4; ++i) acc[i] = (f32x2){0.f, 0.f};
    for (int base = r.x; base < r.y; base += 8) {
        int sidv = (base + li < r.y) ? srcs[base + li] : 0;
        int m = r.y - base; if (m > 8) m = 8;
        for (int j = 0; j < m; ++j) {
            int s = __shfl(sidv, (grp << 3) | j);
            uint4 u = *(const uint4*)(Xb + (size_t)s * D + li * 8);
            acc[0] += (f32x2){bflo(u.x), bfhi(u.x)};
            acc[1] += (f32x2){bflo(u.y), bfhi(u.y)};
            acc[2] += (f32x2){bflo(u.z), bfhi(u.z)};
            acc[3] += (f32x2){bflo(u.w), bfhi(u.w)};
        }
    }
    uint4 o;
    o.x = pk_bf16(acc[0].x, acc[0].y);
    o.y = pk_bf16(acc[1].x, acc[1].y);
    o.z = pk_bf16(acc[2].x, acc[2].y);
    o.w = pk_bf16(acc[3].x, acc[3].y);
    *(uint4*)(Ab + (size_t)node * D + li * 8) = o;
}

// ---------------- fused combine (MFMA), weights staged in LDS ----------------
template <bool USE_IDB>
__global__ __launch_bounds__(256) void k_combine(
    const unsigned short* Xb, const unsigned short* __restrict__ Ab,
    const unsigned short* __restrict__ Wct,
    const unsigned short* __restrict__ Wlt, const float* __restrict__ bl,
    const unsigned short* __restrict__ Wgt, const float* __restrict__ bg,
    const float* __restrict__ IDf, const unsigned short* __restrict__ IDb,
    unsigned short* Ob, float* Of, int N)
{
    __shared__ unsigned short Wc_s[64 * WS], Wl_s[64 * WS], Wg_s[64 * WS];
    __shared__ unsigned short tl[4][16][72];
    int lane = threadIdx.x & 63, w = threadIdx.x >> 6;
    int cl = lane & 15, g = lane >> 4;
    int ntiles = (N + 63) / 64;

    for (int i = threadIdx.x; i < 512; i += 256) {
        int r = i >> 3, c8 = (i & 7) << 3;
        *(uint4*)(Wc_s + r * WS + c8) = *(const uint4*)(Wct + r * 64 + c8);
        *(uint4*)(Wl_s + r * WS + c8) = *(const uint4*)(Wlt + r * 64 + c8);
        *(uint4*)(Wg_s + r * WS + c8) = *(const uint4*)(Wgt + r * 64 + c8);
    }
    float blv[4], bgv[4];
#pragma unroll
    for (int nt = 0; nt < 4; ++nt) {
        blv[nt] = bl[nt * 16 + cl];
        bgv[nt] = bg[nt * 16 + cl];
    }
    __syncthreads();

    for (int tb = blockIdx.x; tb < ntiles; tb += gridDim.x) {
        int node0 = tb * 64 + w * 16;
        bool active = node0 < N;
        f32x4 accL[4], accG[4];
        if (active) {
            const bf16x8* xr = (const bf16x8*)(Xb + (size_t)(node0 + cl) * D + g * 8);
            const bf16x8* ar = (const bf16x8*)(Ab + (size_t)(node0 + cl) * D + g * 8);
            bf16x8 xf0 = xr[0], xf1 = xr[4];
            bf16x8 af0 = ar[0], af1 = ar[4];
            f32x4 accC[4];
#pragma unroll
            for (int nt = 0; nt < 4; ++nt) {
                int wo = (nt * 16 + cl) * WS + g * 8;
                f32x4 z = (f32x4){0.f, 0.f, 0.f, 0.f};
                accL[nt] = __builtin_amdgcn_mfma_f32_16x16x32_bf16(xf1,
                            *(const bf16x8*)(Wl_s + wo + 32),
                            __builtin_amdgcn_mfma_f32_16x16x32_bf16(xf0,
                                *(const bf16x8*)(Wl_s + wo), z, 0, 0, 0), 0, 0, 0);
                accC[nt] = __builtin_amdgcn_mfma_f32_16x16x32_bf16(af1,
                            *(const bf16x8*)(Wc_s + wo + 32),
                            __builtin_amdgcn_mfma_f32_16x16x32_bf16(af0,
                                *(const bf16x8*)(Wc_s + wo), z, 0, 0, 0), 0, 0, 0);
            }
#pragma unroll
            for (int nt = 0; nt < 4; ++nt)
#pragma unroll
                for (int i = 0; i < 4; ++i)
                    tl[w][g * 4 + i][nt * 16 + cl] = f2bf(leaky(accC[nt][i]));
        }
        __syncthreads();
        if (active) {
            const bf16x8* tr = (const bf16x8*)&tl[w][cl][g * 8];
            bf16x8 tf0 = tr[0], tf1 = tr[4];
#pragma unroll
            for (int nt = 0; nt < 4; ++nt) {
                int wo = (nt * 16 + cl) * WS + g * 8;
                f32x4 z = (f32x4){0.f, 0.f, 0.f, 0.f};
                accG[nt] = __builtin_amdgcn_mfma_f32_16x16x32_bf16(tf1,
                            *(const bf16x8*)(Wg_s + wo + 32),
                            __builtin_amdgcn_mfma_f32_16x16x32_bf16(tf0,
                                *(const bf16x8*)(Wg_s + wo), z, 0, 0, 0), 0, 0, 0);
            }
#pragma unroll
            for (int nt = 0; nt < 4; ++nt) {
                int col = nt * 16 + cl;
#pragma unroll
                for (int i = 0; i < 4; ++i) {
                    size_t row = (size_t)(node0 + g * 4 + i);
                    float idv = USE_IDB ? bflo((unsigned)IDb[row * D + col])
                                        : IDf[row * D + col];
                    float xh = leaky(accL[nt][i] + blv[nt]) + idv;
                    float o = leaky(accG[nt][i] + bgv[nt] + xh);
                    if (Ob) Ob[row * D + col] = f2bf(o);
                    else    Of[row * D + col] = o;
                }
            }
        }
        __syncthreads();
    }
}

extern "C" void kernel_launch(void* const* d_in, const int* in_sizes, int n_in,
                              void* d_out, int out_size, void* d_ws, size_t ws_size,
                              hipStream_t stream)
{
    const float* features = (const float*)d_in[0];
    const float* id_emb   = (const float*)d_in[1];
    const int*   eidx     = (const int*)d_in[2];
    const float* W_mlp    = (const float*)d_in[3];
    const float* b_mlp    = (const float*)d_in[4];
    const float* Wc1 = (const float*)d_in[5];
    const float* Wl1 = (const float*)d_in[6];
    const float* bl1 = (const float*)d_in[7];
    const float* Wg1 = (const float*)d_in[8];
    const float* bg1 = (const float*)d_in[9];
    const float* Wc2 = (const float*)d_in[10];
    const float* Wl2 = (const float*)d_in[11];
    const float* bl2 = (const float*)d_in[12];
    const float* Wg2 = (const float*)d_in[13];
    const float* bg2 = (const float*)d_in[14];

    int N = in_sizes[0] / D_FEAT;
    int E = in_sizes[2] / 2;
    const int* esrc = eidx;
    const int* edst = eidx + E;
    int nbk = (N + BW - 1) >> BSH;               // 782 for N=100000

    char* wp = (char*)d_ws;
    unsigned short* Xb = (unsigned short*)wp;              wp += (size_t)N * D * 2;
    unsigned short* Ab = (unsigned short*)wp;              wp += (size_t)N * D * 2;
    int* srcs = (int*)wp;                                  wp += (size_t)nbk * CAP * 4;
    int2* rng = (int2*)wp;                                 wp += (size_t)N * 8;
    int* gcur = (int*)wp;                                  wp += 1024 * GST * 4;
    unsigned short* wt = (unsigned short*)wp;              wp += (8192 + 6 * 4096) * 2;
    unsigned char* Xf8 = (unsigned char*)wp;               wp += (size_t)N * D;
    unsigned short* IDb = (unsigned short*)wp;             wp += (size_t)N * D * 2;
    bool use_idb = ((size_t)(wp - (char*)d_ws) <= ws_size);
    if (!use_idb) IDb = nullptr;

    unsigned short* Wmt  = wt;
    unsigned short* Wct1 = wt + 8192;
    unsigned short* Wlt1 = Wct1 + 4096;
    unsigned short* Wgt1 = Wlt1 + 4096;
    unsigned short* Wct2 = Wgt1 + 4096;
    unsigned short* Wlt2 = Wct2 + 4096;
    unsigned short* Wgt2 = Wlt2 + 4096;

    // pairs scratch lives in d_out (25.6 MB >= nbk*CAP*4 = 8.0 MB); fully dead
    // before the final combine writes d_out.
    unsigned* pairs = (unsigned*)d_out;

    dim3 blk(256);
    int egrid = (E + 4095) / 4096;               // 391 partition blocks
    int cgrid = 782;                             // ~3 blocks/CU, 2 tiles each
    int ggrid = (N + 31) / 32;                   // 8 nodes per wave
    int pgrid = egrid + 512 + (use_idb ? NID : 0);

    P7 p7;
    p7.w[0] = W_mlp; p7.w[1] = Wc1; p7.w[2] = Wl1; p7.w[3] = Wg1;
    p7.w[4] = Wc2; p7.w[5] = Wl2; p7.w[6] = Wg2;

    // weight transpose + gcur init (one dispatch)
    k_prep<<<8, blk, 0, stream>>>(p7, wt, gcur, nbk);

    // edge partition || MLP || id->bf16 (independent -> one dispatch)
    k_partmlp<<<pgrid, blk, 0, stream>>>(esrc, edst, gcur, pairs, E, egrid,
                                         features, Wmt, b_mlp, Xb, Xf8,
                                         id_emb, IDb, N);

    // per-bucket sort -> per-node CSR
    k_sort<<<nbk, blk, 0, stream>>>(pairs, gcur, rng, srcs, N);

    // layer 1: fp8 gather (x small after L2-norm -> negligible fp8 error)
    k_gather8<<<ggrid, blk, 0, stream>>>(rng, srcs, Xf8, Ab, N);
    if (use_idb)
        k_combine<true><<<cgrid, blk, 0, stream>>>(Xb, Ab, Wct1, Wlt1, bl1, Wgt1, bg1,
                                                   id_emb, IDb, Xb, (float*)nullptr, N);
    else
        k_combine<false><<<cgrid, blk, 0, stream>>>(Xb, Ab, Wct1, Wlt1, bl1, Wgt1, bg1,
                                                    id_emb, IDb, Xb, (float*)nullptr, N);

    // layer 2: bf16 gather (x1 is id_emb-dominated, fp8 too lossy)
    k_gather<<<ggrid, blk, 0, stream>>>(rng, srcs, Xb, Ab, N);
    if (use_idb)
        k_combine<true><<<cgrid, blk, 0, stream>>>(Xb, Ab, Wct2, Wlt2, bl2, Wgt2, bg2,
                                                   id_emb, IDb,
                                                   (unsigned short*)nullptr, (float*)d_out, N);
    else
        k_combine<false><<<cgrid, blk, 0, stream>>>(Xb, Ab, Wct2, Wlt2, bl2, Wgt2, bg2,
                                                    id_emb, IDb,
                                                    (unsigned short*)nullptr, (float*)d_out, N);
}

// Round 17
// 159.056 us; speedup vs baseline: 1.0122x; 1.0122x over previous
//
#include <hip/hip_runtime.h>
#include <cstdint>
#include <cstddef>

#define D 64
#define D_FEAT 128
#define SLOPE 0.01f
#define BSH 7                 // bucket = dst >> 7  (128 nodes per bucket)
#define BW 128
#define CAP 2560              // per-bucket slot capacity (mean 2046, +11 sigma)
#define WS 72                 // LDS weight row stride (bf16): 144B, 16B-aligned, 2-way banks
#define GST 16                // gcur stride (ints): one counter per 64B line

typedef __attribute__((ext_vector_type(8))) short bf16x8;
typedef __attribute__((ext_vector_type(4))) float f32x4;
typedef __attribute__((ext_vector_type(2))) float f32x2;

struct P7 { const float* w[7]; };

__device__ __forceinline__ float leaky(float v) { return v >= 0.f ? v : SLOPE * v; }

__device__ __forceinline__ unsigned short f2bf(float f) {
    union { float f; unsigned u; } v; v.f = f;
    unsigned r = v.u + 0x7FFF + ((v.u >> 16) & 1);   // RNE
    return (unsigned short)(r >> 16);
}
__device__ __forceinline__ float bflo(unsigned u) {
    union { unsigned x; float f; } v; v.x = u << 16; return v.f;
}
__device__ __forceinline__ float bfhi(unsigned u) {
    union { unsigned x; float f; } v; v.x = u & 0xFFFF0000u; return v.f;
}
// one-instruction packed f32->2xbf16 (RNE); no builtin on gfx950
__device__ __forceinline__ unsigned pk_bf16(float lo, float hi) {
    unsigned r;
    asm("v_cvt_pk_bf16_f32 %0, %1, %2" : "=v"(r) : "v"(lo), "v"(hi));
    return r;
}

// ---------------- prep: weights fp32 row-major -> bf16 col-major; + gcur init --
__global__ __launch_bounds__(256) void k_prep(P7 p, unsigned short* __restrict__ out,
    int* __restrict__ gcur, int nbk)
{
    int m = blockIdx.x;
    if (m == 7) {
        for (int i = threadIdx.x; i < nbk; i += 256) gcur[i * GST] = i * CAP;
        return;
    }
    int K = (m == 0) ? 128 : 64;
    const float* W = p.w[m];
    unsigned short* o = out + ((m == 0) ? 0 : 8192 + (m - 1) * 4096);
    int total = K * 64;
    for (int i = threadIdx.x; i < total; i += 256) {
        int col = i / K, k = i - col * K;
        o[i] = f2bf(W[k * 64 + col]);     // o[col*K + k]
    }
}

// ---------------- fused: edge partition (blocks 0..nPart-1) || MLP (rest) ------
// partition: single-pass, 4096 edges/block, register-staged
__global__ __launch_bounds__(256) void k_partmlp(
    const int* __restrict__ esrc, const int* __restrict__ edst,
    int* __restrict__ gcur, unsigned* __restrict__ pairs, int E, int nPart,
    const float* __restrict__ F, const unsigned short* __restrict__ Wt,
    const float* __restrict__ bm,
    unsigned short* __restrict__ Xb, unsigned char* __restrict__ Xf8, int N)
{
    __shared__ int lcnt[1024];
    __shared__ int lbase[1024];
    if ((int)blockIdx.x < nPart) {
        int base = blockIdx.x * 4096;
        for (int i = threadIdx.x; i < 1024; i += 256) lcnt[i] = 0;
        __syncthreads();
        int dv[16], rv[16];
#pragma unroll
        for (int i = 0; i < 16; ++i) {
            int e = base + i * 256 + threadIdx.x;
            if (e < E) {
                dv[i] = edst[e];
                rv[i] = atomicAdd(&lcnt[dv[i] >> BSH], 1);
            } else dv[i] = -1;
        }
        __syncthreads();
        for (int i = threadIdx.x; i < 1024; i += 256) {
            int c = lcnt[i];
            lbase[i] = c ? atomicAdd(&gcur[i * GST], c) : 0;   // line-padded counters
        }
        __syncthreads();
#pragma unroll
        for (int i = 0; i < 16; ++i) {
            if (dv[i] >= 0) {
                int e = base + i * 256 + threadIdx.x;
                unsigned pk = ((unsigned)(dv[i] & (BW - 1)) << 25) | (unsigned)esrc[e];
                pairs[lbase[dv[i] >> BSH] + rv[i]] = pk;
            }
        }
        return;
    }
    // ---- MLP branch: x = L2norm(F@Wm + bm) -> bf16 + fp8 ----
    int lane = threadIdx.x & 63, w = threadIdx.x >> 6;
    int cl = lane & 15, g = lane >> 4;
    int ntiles = (N + 63) / 64;
    int tb0 = blockIdx.x - nPart;
    int step = gridDim.x - nPart;

    bf16x8 Wmf[4][4];
#pragma unroll
    for (int ks = 0; ks < 4; ++ks)
#pragma unroll
        for (int nt = 0; nt < 4; ++nt)
            Wmf[ks][nt] = *(const bf16x8*)(Wt + (nt * 16 + cl) * 128 + ks * 32 + g * 8);
    float bmv[4];
#pragma unroll
    for (int nt = 0; nt < 4; ++nt) bmv[nt] = bm[nt * 16 + cl];

    for (int tb = tb0; tb < ntiles; tb += step) {
        int node0 = tb * 64 + w * 16;
        if (node0 >= N) continue;
        f32x4 acc[4];
#pragma unroll
        for (int nt = 0; nt < 4; ++nt) acc[nt] = (f32x4){0.f, 0.f, 0.f, 0.f};
#pragma unroll
        for (int ks = 0; ks < 4; ++ks) {
            const float4* fp = (const float4*)(F + (size_t)(node0 + cl) * D_FEAT + ks * 32 + g * 8);
            float4 a = fp[0], b = fp[1];
            bf16x8 af;
            af[0] = (short)f2bf(a.x); af[1] = (short)f2bf(a.y);
            af[2] = (short)f2bf(a.z); af[3] = (short)f2bf(a.w);
            af[4] = (short)f2bf(b.x); af[5] = (short)f2bf(b.y);
            af[6] = (short)f2bf(b.z); af[7] = (short)f2bf(b.w);
#pragma unroll
            for (int nt = 0; nt < 4; ++nt)
                acc[nt] = __builtin_amdgcn_mfma_f32_16x16x32_bf16(af, Wmf[ks][nt], acc[nt], 0, 0, 0);
        }
        float ss[4] = {0.f, 0.f, 0.f, 0.f};
#pragma unroll
        for (int nt = 0; nt < 4; ++nt)
#pragma unroll
            for (int i = 0; i < 4; ++i) {
                float v = acc[nt][i] + bmv[nt];
                acc[nt][i] = v;
                ss[i] += v * v;
            }
#pragma unroll
        for (int off = 8; off >= 1; off >>= 1)
#pragma unroll
            for (int i = 0; i < 4; ++i)
                ss[i] += __shfl_xor(ss[i], off);
        float inv[4];
#pragma unroll
        for (int i = 0; i < 4; ++i)
            inv[i] = 1.f / fmaxf(sqrtf(ss[i]), 1e-12f);
#pragma unroll
        for (int nt = 0; nt < 4; ++nt)
#pragma unroll
            for (int i = 0; i < 4; ++i) {
                float v = acc[nt][i] * inv[i];
                size_t row = (size_t)(node0 + g * 4 + i);
                Xb[row * D + nt * 16 + cl] = f2bf(v);
                int p8 = __builtin_amdgcn_cvt_pk_fp8_f32(v, v, 0, false);
                Xf8[row * D + nt * 16 + cl] = (unsigned char)(p8 & 0xFF);
            }
    }
}

// ---------------- per-bucket counting sort -> per-node ranges (coalesced) ------
__global__ __launch_bounds__(256) void k_sort(const unsigned* __restrict__ pairs,
    const int* __restrict__ gcur, int2* __restrict__ rng,
    int* __restrict__ srcs, int N)
{
    __shared__ int lh[BW];
    __shared__ int cur[BW];
    __shared__ unsigned buf[CAP];
    int b = blockIdx.x;
    int node0 = b << BSH;
    int s0 = b * CAP;
    int cnt = gcur[b * GST] - s0;
    if (threadIdx.x < BW) lh[threadIdx.x] = 0;
    __syncthreads();
    for (int i = threadIdx.x; i < cnt; i += 256)
        atomicAdd(&lh[pairs[s0 + i] >> 25], 1);
    __syncthreads();
    if (threadIdx.x < 64) {   // wave 0: exclusive scan of 128 counts, 2/lane
        int a = lh[2 * threadIdx.x], c = lh[2 * threadIdx.x + 1];
        int s = a + c, inc = s;
#pragma unroll
        for (int d = 1; d < 64; d <<= 1) {
            int u = __shfl_up(inc, d);
            if ((int)threadIdx.x >= d) inc += u;
        }
        int ex = inc - s;
        cur[2 * threadIdx.x] = ex;
        cur[2 * threadIdx.x + 1] = ex + a;
    }
    __syncthreads();
    if (threadIdx.x < BW) {
        int node = node0 + threadIdx.x;
        if (node < N)
            rng[node] = make_int2(s0 + cur[threadIdx.x],
                                  s0 + cur[threadIdx.x] + lh[threadIdx.x]);
    }
    __syncthreads();
    for (int i = threadIdx.x; i < cnt; i += 256) {
        unsigned p = pairs[s0 + i];
        int r = atomicAdd(&cur[p >> 25], 1);
        buf[r] = p & 0x1FFFFFFu;
    }
    __syncthreads();
    for (int i = threadIdx.x; i < cnt; i += 256)
        srcs[s0 + i] = (int)buf[i];
}

// ---------------- gather (fp8 rows): 8-lane group per node, no cross-group reduce
__global__ __launch_bounds__(256) void k_gather8(const int2* __restrict__ rng,
    const int* __restrict__ srcs,
    const unsigned char* __restrict__ Xf8, unsigned short* __restrict__ Ab, int N)
{
    int lane = threadIdx.x & 63, w = threadIdx.x >> 6;
    int grp = lane >> 3, li = lane & 7;     // group owns one node; li = col block
    int node = blockIdx.x * 32 + w * 8 + grp;
    if (node >= N) return;
    int2 r = rng[node];
    f32x2 acc[4];
#pragma unroll
    for (int i = 0; i < 4; ++i) acc[i] = (f32x2){0.f, 0.f};
    for (int base = r.x; base < r.y; base += 8) {
        int sidv = (base + li < r.y) ? srcs[base + li] : 0;   // 8 sids per group
        int m = r.y - base; if (m > 8) m = 8;
        for (int j = 0; j < m; ++j) {
            int s = __shfl(sidv, (grp << 3) | j);
            uint2 u = *(const uint2*)(Xf8 + (size_t)s * D + li * 8);
            acc[0] += __builtin_amdgcn_cvt_pk_f32_fp8(u.x, false);
            acc[1] += __builtin_amdgcn_cvt_pk_f32_fp8(u.x, true);
            acc[2] += __builtin_amdgcn_cvt_pk_f32_fp8(u.y, false);
            acc[3] += __builtin_amdgcn_cvt_pk_f32_fp8(u.y, true);
        }
    }
    uint4 o;
    o.x = pk_bf16(acc[0].x, acc[0].y);
    o.y = pk_bf16(acc[1].x, acc[1].y);
    o.z = pk_bf16(acc[2].x, acc[2].y);
    o.w = pk_bf16(acc[3].x, acc[3].y);
    *(uint4*)(Ab + (size_t)node * D + li * 8) = o;
}

// ---------------- gather (bf16 rows): layer 2, same group-per-node structure ---
__global__ __launch_bounds__(256) void k_gather(const int2* __restrict__ rng,
    const int* __restrict__ srcs,
    const unsigned short* __restrict__ Xb, unsigned short* __restrict__ Ab, int N)
{
    int lane = threadIdx.x & 63, w = threadIdx.x >> 6;
    int grp = lane >> 3, li = lane & 7;
    int node = blockIdx.x * 32 + w * 8 + grp;
    if (node >= N) return;
    int2 r = rng[node];
    f32x2 acc[4];
#pragma unroll
    for (int i = 0; i < 4; ++i) acc[i] = (f32x2){0.f, 0.f};
    for (int base = r.x; base < r.y; base += 8) {
        int sidv = (base + li < r.y) ? srcs[base + li] : 0;
        int m = r.y - base; if (m > 8) m = 8;
        for (int j = 0; j < m; ++j) {
            int s = __shfl(sidv, (grp << 3) | j);
            uint4 u = *(const uint4*)(Xb + (size_t)s * D + li * 8);
            acc[0] += (f32x2){bflo(u.x), bfhi(u.x)};
            acc[1] += (f32x2){bflo(u.y), bfhi(u.y)};
            acc[2] += (f32x2){bflo(u.z), bfhi(u.z)};
            acc[3] += (f32x2){bflo(u.w), bfhi(u.w)};
        }
    }
    uint4 o;
    o.x = pk_bf16(acc[0].x, acc[0].y);
    o.y = pk_bf16(acc[1].x, acc[1].y);
    o.z = pk_bf16(acc[2].x, acc[2].y);
    o.w = pk_bf16(acc[3].x, acc[3].y);
    *(uint4*)(Ab + (size_t)node * D + li * 8) = o;
}

// ---------------- fused combine (MFMA), weights staged in LDS ----------------
__global__ __launch_bounds__(256) void k_combine(
    const unsigned short* Xb, const unsigned short* __restrict__ Ab,
    const unsigned short* __restrict__ Wct,
    const unsigned short* __restrict__ Wlt, const float* __restrict__ bl,
    const unsigned short* __restrict__ Wgt, const float* __restrict__ bg,
    const float* __restrict__ ID,
    unsigned short* Ob, float* Of, int N)
{
    __shared__ unsigned short Wc_s[64 * WS], Wl_s[64 * WS], Wg_s[64 * WS];
    __shared__ unsigned short tl[4][16][72];
    int lane = threadIdx.x & 63, w = threadIdx.x >> 6;
    int cl = lane & 15, g = lane >> 4;
    int ntiles = (N + 63) / 64;

    for (int i = threadIdx.x; i < 512; i += 256) {
        int r = i >> 3, c8 = (i & 7) << 3;
        *(uint4*)(Wc_s + r * WS + c8) = *(const uint4*)(Wct + r * 64 + c8);
        *(uint4*)(Wl_s + r * WS + c8) = *(const uint4*)(Wlt + r * 64 + c8);
        *(uint4*)(Wg_s + r * WS + c8) = *(const uint4*)(Wgt + r * 64 + c8);
    }
    float blv[4], bgv[4];
#pragma unroll
    for (int nt = 0; nt < 4; ++nt) {
        blv[nt] = bl[nt * 16 + cl];
        bgv[nt] = bg[nt * 16 + cl];
    }
    __syncthreads();

    for (int tb = blockIdx.x; tb < ntiles; tb += gridDim.x) {
        int node0 = tb * 64 + w * 16;
        bool active = node0 < N;
        f32x4 accL[4], accG[4];
        if (active) {
            const bf16x8* xr = (const bf16x8*)(Xb + (size_t)(node0 + cl) * D + g * 8);
            const bf16x8* ar = (const bf16x8*)(Ab + (size_t)(node0 + cl) * D + g * 8);
            bf16x8 xf0 = xr[0], xf1 = xr[4];
            bf16x8 af0 = ar[0], af1 = ar[4];
            f32x4 accC[4];
#pragma unroll
            for (int nt = 0; nt < 4; ++nt) {
                int wo = (nt * 16 + cl) * WS + g * 8;
                f32x4 z = (f32x4){0.f, 0.f, 0.f, 0.f};
                accL[nt] = __builtin_amdgcn_mfma_f32_16x16x32_bf16(xf1,
                            *(const bf16x8*)(Wl_s + wo + 32),
                            __builtin_amdgcn_mfma_f32_16x16x32_bf16(xf0,
                                *(const bf16x8*)(Wl_s + wo), z, 0, 0, 0), 0, 0, 0);
                accC[nt] = __builtin_amdgcn_mfma_f32_16x16x32_bf16(af1,
                            *(const bf16x8*)(Wc_s + wo + 32),
                            __builtin_amdgcn_mfma_f32_16x16x32_bf16(af0,
                                *(const bf16x8*)(Wc_s + wo), z, 0, 0, 0), 0, 0, 0);
            }
#pragma unroll
            for (int nt = 0; nt < 4; ++nt)
#pragma unroll
                for (int i = 0; i < 4; ++i)
                    tl[w][g * 4 + i][nt * 16 + cl] = f2bf(leaky(accC[nt][i]));
        }
        __syncthreads();
        if (active) {
            const bf16x8* tr = (const bf16x8*)&tl[w][cl][g * 8];
            bf16x8 tf0 = tr[0], tf1 = tr[4];
#pragma unroll
            for (int nt = 0; nt < 4; ++nt) {
                int wo = (nt * 16 + cl) * WS + g * 8;
                f32x4 z = (f32x4){0.f, 0.f, 0.f, 0.f};
                accG[nt] = __builtin_amdgcn_mfma_f32_16x16x32_bf16(tf1,
                            *(const bf16x8*)(Wg_s + wo + 32),
                            __builtin_amdgcn_mfma_f32_16x16x32_bf16(tf0,
                                *(const bf16x8*)(Wg_s + wo), z, 0, 0, 0), 0, 0, 0);
            }
#pragma unroll
            for (int nt = 0; nt < 4; ++nt) {
                int col = nt * 16 + cl;
#pragma unroll
                for (int i = 0; i < 4; ++i) {
                    size_t row = (size_t)(node0 + g * 4 + i);
                    float xh = leaky(accL[nt][i] + blv[nt]) + ID[row * D + col];
                    float o = leaky(accG[nt][i] + bgv[nt] + xh);
                    if (Ob) Ob[row * D + col] = f2bf(o);
                    else    Of[row * D + col] = o;
                }
            }
        }
        __syncthreads();
    }
}

extern "C" void kernel_launch(void* const* d_in, const int* in_sizes, int n_in,
                              void* d_out, int out_size, void* d_ws, size_t ws_size,
                              hipStream_t stream)
{
    const float* features = (const float*)d_in[0];
    const float* id_emb   = (const float*)d_in[1];
    const int*   eidx     = (const int*)d_in[2];
    const float* W_mlp    = (const float*)d_in[3];
    const float* b_mlp    = (const float*)d_in[4];
    const float* Wc1 = (const float*)d_in[5];
    const float* Wl1 = (const float*)d_in[6];
    const float* bl1 = (const float*)d_in[7];
    const float* Wg1 = (const float*)d_in[8];
    const float* bg1 = (const float*)d_in[9];
    const float* Wc2 = (const float*)d_in[10];
    const float* Wl2 = (const float*)d_in[11];
    const float* bl2 = (const float*)d_in[12];
    const float* Wg2 = (const float*)d_in[13];
    const float* bg2 = (const float*)d_in[14];

    int N = in_sizes[0] / D_FEAT;
    int E = in_sizes[2] / 2;
    const int* esrc = eidx;
    const int* edst = eidx + E;
    int nbk = (N + BW - 1) >> BSH;               // 782 for N=100000

    char* wp = (char*)d_ws;
    unsigned short* Xb = (unsigned short*)wp;              wp += (size_t)N * D * 2;
    unsigned short* Ab = (unsigned short*)wp;              wp += (size_t)N * D * 2;
    int* srcs = (int*)wp;                                  wp += (size_t)nbk * CAP * 4;
    int2* rng = (int2*)wp;                                 wp += (size_t)N * 8;
    int* gcur = (int*)wp;                                  wp += 1024 * GST * 4;
    unsigned short* wt = (unsigned short*)wp;              wp += (8192 + 6 * 4096) * 2;
    unsigned char* Xf8 = (unsigned char*)wp;               wp += (size_t)N * D;

    unsigned short* Wmt  = wt;
    unsigned short* Wct1 = wt + 8192;
    unsigned short* Wlt1 = Wct1 + 4096;
    unsigned short* Wgt1 = Wlt1 + 4096;
    unsigned short* Wct2 = Wgt1 + 4096;
    unsigned short* Wlt2 = Wct2 + 4096;
    unsigned short* Wgt2 = Wlt2 + 4096;

    // pairs scratch lives in d_out (25.6 MB >= nbk*CAP*4 = 8.0 MB); fully dead
    // before the final combine writes d_out.
    unsigned* pairs = (unsigned*)d_out;

    dim3 blk(256);
    int egrid = (E + 4095) / 4096;               // 391 partition blocks
    int cgrid = 782;                             // ~3 blocks/CU, 2 tiles each
    int ggrid = (N + 31) / 32;                   // 8 nodes per wave

    P7 p7;
    p7.w[0] = W_mlp; p7.w[1] = Wc1; p7.w[2] = Wl1; p7.w[3] = Wg1;
    p7.w[4] = Wc2; p7.w[5] = Wl2; p7.w[6] = Wg2;

    // weight transpose + gcur init (one dispatch)
    k_prep<<<8, blk, 0, stream>>>(p7, wt, gcur, nbk);

    // edge partition || MLP (independent -> one dispatch)
    k_partmlp<<<egrid + 512, blk, 0, stream>>>(esrc, edst, gcur, pairs, E, egrid,
                                               features, Wmt, b_mlp, Xb, Xf8, N);

    // per-bucket sort -> per-node CSR
    k_sort<<<nbk, blk, 0, stream>>>(pairs, gcur, rng, srcs, N);

    // layer 1: fp8 gather (x small after L2-norm -> negligible fp8 error)
    k_gather8<<<ggrid, blk, 0, stream>>>(rng, srcs, Xf8, Ab, N);
    k_combine<<<cgrid, blk, 0, stream>>>(Xb, Ab, Wct1, Wlt1, bl1, Wgt1, bg1, id_emb,
                                         Xb, (float*)nullptr, N);

    // layer 2: bf16 gather (x1 is id_emb-dominated, fp8 too lossy)
    k_gather<<<ggrid, blk, 0, stream>>>(rng, srcs, Xb, Ab, N);
    k_combine<<<cgrid, blk, 0, stream>>>(Xb, Ab, Wct2, Wlt2, bl2, Wgt2, bg2, id_emb,
                                         (unsigned short*)nullptr, (float*)d_out, N);
}

// Round 18
// 147.630 us; speedup vs baseline: 1.0906x; 1.0774x over previous
//
#include <hip/hip_runtime.h>
#include <cstdint>
#include <cstddef>

#define D 64
#define D_FEAT 128
#define SLOPE 0.01f
#define BSH 7                 // bucket = dst >> 7  (128 nodes per bucket)
#define BW 128
#define CAP 2560              // per-bucket slot capacity (mean 2046, +11 sigma)
#define WS 72                 // LDS weight row stride (bf16): 144B, 16B-aligned, 2-way banks

typedef __attribute__((ext_vector_type(8))) short bf16x8;
typedef __attribute__((ext_vector_type(4))) float f32x4;
typedef __attribute__((ext_vector_type(2))) float f32x2;

struct P7 { const float* w[7]; };

__device__ __forceinline__ float leaky(float v) { return v >= 0.f ? v : SLOPE * v; }

__device__ __forceinline__ unsigned short f2bf(float f) {
    union { float f; unsigned u; } v; v.f = f;
    unsigned r = v.u + 0x7FFF + ((v.u >> 16) & 1);   // RNE
    return (unsigned short)(r >> 16);
}
__device__ __forceinline__ float bflo(unsigned u) {
    union { unsigned x; float f; } v; v.x = u << 16; return v.f;
}
__device__ __forceinline__ float bfhi(unsigned u) {
    union { unsigned x; float f; } v; v.x = u & 0xFFFF0000u; return v.f;
}
// one-instruction packed f32->2xbf16 (RNE); no builtin on gfx950
__device__ __forceinline__ unsigned pk_bf16(float lo, float hi) {
    unsigned r;
    asm("v_cvt_pk_bf16_f32 %0, %1, %2" : "=v"(r) : "v"(lo), "v"(hi));
    return r;
}

// ---------------- prep: weights fp32 row-major -> bf16 col-major; + gcur init --
__global__ __launch_bounds__(256) void k_prep(P7 p, unsigned short* __restrict__ out,
    int* __restrict__ gcur, int nbk)
{
    int m = blockIdx.x;
    if (m == 7) {
        for (int i = threadIdx.x; i < nbk; i += 256) gcur[i] = i * CAP;
        return;
    }
    int K = (m == 0) ? 128 : 64;
    const float* W = p.w[m];
    unsigned short* o = out + ((m == 0) ? 0 : 8192 + (m - 1) * 4096);
    int total = K * 64;
    for (int i = threadIdx.x; i < total; i += 256) {
        int col = i / K, k = i - col * K;
        o[i] = f2bf(W[k * 64 + col]);     // o[col*K + k]
    }
}

// ---------------- fused: edge partition (blocks 0..nPart-1) || MLP (rest) ------
// partition: single-pass, 4096 edges/block, register-staged
__global__ __launch_bounds__(256) void k_partmlp(
    const int* __restrict__ esrc, const int* __restrict__ edst,
    int* __restrict__ gcur, unsigned* __restrict__ pairs, int E, int nPart,
    const float* __restrict__ F, const unsigned short* __restrict__ Wt,
    const float* __restrict__ bm,
    unsigned short* __restrict__ Xb, unsigned char* __restrict__ Xf8, int N)
{
    __shared__ int lcnt[1024];
    __shared__ int lbase[1024];
    if ((int)blockIdx.x < nPart) {
        int base = blockIdx.x * 4096;
        for (int i = threadIdx.x; i < 1024; i += 256) lcnt[i] = 0;
        __syncthreads();
        int dv[16], rv[16];
#pragma unroll
        for (int i = 0; i < 16; ++i) {
            int e = base + i * 256 + threadIdx.x;
            if (e < E) {
                dv[i] = edst[e];
                rv[i] = atomicAdd(&lcnt[dv[i] >> BSH], 1);
            } else dv[i] = -1;
        }
        __syncthreads();
        for (int i = threadIdx.x; i < 1024; i += 256) {
            int c = lcnt[i];
            lbase[i] = c ? atomicAdd(&gcur[i], c) : 0;
        }
        __syncthreads();
#pragma unroll
        for (int i = 0; i < 16; ++i) {
            if (dv[i] >= 0) {
                int e = base + i * 256 + threadIdx.x;
                unsigned pk = ((unsigned)(dv[i] & (BW - 1)) << 25) | (unsigned)esrc[e];
                pairs[lbase[dv[i] >> BSH] + rv[i]] = pk;
            }
        }
        return;
    }
    // ---- MLP branch: x = L2norm(F@Wm + bm) -> bf16 + fp8 ----
    int lane = threadIdx.x & 63, w = threadIdx.x >> 6;
    int cl = lane & 15, g = lane >> 4;
    int ntiles = (N + 63) / 64;
    int tb0 = blockIdx.x - nPart;
    int step = gridDim.x - nPart;

    bf16x8 Wmf[4][4];
#pragma unroll
    for (int ks = 0; ks < 4; ++ks)
#pragma unroll
        for (int nt = 0; nt < 4; ++nt)
            Wmf[ks][nt] = *(const bf16x8*)(Wt + (nt * 16 + cl) * 128 + ks * 32 + g * 8);
    float bmv[4];
#pragma unroll
    for (int nt = 0; nt < 4; ++nt) bmv[nt] = bm[nt * 16 + cl];

    for (int tb = tb0; tb < ntiles; tb += step) {
        int node0 = tb * 64 + w * 16;
        if (node0 >= N) continue;
        f32x4 acc[4];
#pragma unroll
        for (int nt = 0; nt < 4; ++nt) acc[nt] = (f32x4){0.f, 0.f, 0.f, 0.f};
#pragma unroll
        for (int ks = 0; ks < 4; ++ks) {
            const float4* fp = (const float4*)(F + (size_t)(node0 + cl) * D_FEAT + ks * 32 + g * 8);
            float4 a = fp[0], b = fp[1];
            bf16x8 af;
            af[0] = (short)f2bf(a.x); af[1] = (short)f2bf(a.y);
            af[2] = (short)f2bf(a.z); af[3] = (short)f2bf(a.w);
            af[4] = (short)f2bf(b.x); af[5] = (short)f2bf(b.y);
            af[6] = (short)f2bf(b.z); af[7] = (short)f2bf(b.w);
#pragma unroll
            for (int nt = 0; nt < 4; ++nt)
                acc[nt] = __builtin_amdgcn_mfma_f32_16x16x32_bf16(af, Wmf[ks][nt], acc[nt], 0, 0, 0);
        }
        float ss[4] = {0.f, 0.f, 0.f, 0.f};
#pragma unroll
        for (int nt = 0; nt < 4; ++nt)
#pragma unroll
            for (int i = 0; i < 4; ++i) {
                float v = acc[nt][i] + bmv[nt];
                acc[nt][i] = v;
                ss[i] += v * v;
            }
#pragma unroll
        for (int off = 8; off >= 1; off >>= 1)
#pragma unroll
            for (int i = 0; i < 4; ++i)
                ss[i] += __shfl_xor(ss[i], off);
        float inv[4];
#pragma unroll
        for (int i = 0; i < 4; ++i)
            inv[i] = 1.f / fmaxf(sqrtf(ss[i]), 1e-12f);
#pragma unroll
        for (int nt = 0; nt < 4; ++nt)
#pragma unroll
            for (int i = 0; i < 4; ++i) {
                float v = acc[nt][i] * inv[i];
                size_t row = (size_t)(node0 + g * 4 + i);
                Xb[row * D + nt * 16 + cl] = f2bf(v);
                int p8 = __builtin_amdgcn_cvt_pk_fp8_f32(v, v, 0, false);
                Xf8[row * D + nt * 16 + cl] = (unsigned char)(p8 & 0xFF);
            }
    }
}

// ---------------- per-bucket counting sort -> per-node ranges (coalesced) ------
__global__ __launch_bounds__(256) void k_sort(const unsigned* __restrict__ pairs,
    const int* __restrict__ gcur, int2* __restrict__ rng,
    int* __restrict__ srcs, int N)
{
    __shared__ int lh[BW];
    __shared__ int cur[BW];
    __shared__ unsigned buf[CAP];
    int b = blockIdx.x;
    int node0 = b << BSH;
    int s0 = b * CAP;
    int cnt = gcur[b] - s0;
    if (threadIdx.x < BW) lh[threadIdx.x] = 0;
    __syncthreads();
    for (int i = threadIdx.x; i < cnt; i += 256)
        atomicAdd(&lh[pairs[s0 + i] >> 25], 1);
    __syncthreads();
    if (threadIdx.x < 64) {   // wave 0: exclusive scan of 128 counts, 2/lane
        int a = lh[2 * threadIdx.x], c = lh[2 * threadIdx.x + 1];
        int s = a + c, inc = s;
#pragma unroll
        for (int d = 1; d < 64; d <<= 1) {
            int u = __shfl_up(inc, d);
            if ((int)threadIdx.x >= d) inc += u;
        }
        int ex = inc - s;
        cur[2 * threadIdx.x] = ex;
        cur[2 * threadIdx.x + 1] = ex + a;
    }
    __syncthreads();
    if (threadIdx.x < BW) {
        int node = node0 + threadIdx.x;
        if (node < N)
            rng[node] = make_int2(s0 + cur[threadIdx.x],
                                  s0 + cur[threadIdx.x] + lh[threadIdx.x]);
    }
    __syncthreads();
    for (int i = threadIdx.x; i < cnt; i += 256) {
        unsigned p = pairs[s0 + i];
        int r = atomicAdd(&cur[p >> 25], 1);
        buf[r] = p & 0x1FFFFFFu;
    }
    __syncthreads();
    for (int i = threadIdx.x; i < cnt; i += 256)
        srcs[s0 + i] = (int)buf[i];
}

// ---------------- gather (fp8 rows): 8-lane group per node, no cross-group reduce
__global__ __launch_bounds__(256) void k_gather8(const int2* __restrict__ rng,
    const int* __restrict__ srcs,
    const unsigned char* __restrict__ Xf8, unsigned short* __restrict__ Ab, int N)
{
    int lane = threadIdx.x & 63, w = threadIdx.x >> 6;
    int grp = lane >> 3, li = lane & 7;     // group owns one node; li = col block
    int node = blockIdx.x * 32 + w * 8 + grp;
    if (node >= N) return;
    int2 r = rng[node];
    f32x2 acc[4];
#pragma unroll
    for (int i = 0; i < 4; ++i) acc[i] = (f32x2){0.f, 0.f};
    for (int base = r.x; base < r.y; base += 8) {
        int sidv = (base + li < r.y) ? srcs[base + li] : 0;   // 8 sids per group
        int m = r.y - base; if (m > 8) m = 8;
        for (int j = 0; j < m; ++j) {
            int s = __shfl(sidv, (grp << 3) | j);
            uint2 u = *(const uint2*)(Xf8 + (size_t)s * D + li * 8);
            acc[0] += __builtin_amdgcn_cvt_pk_f32_fp8(u.x, false);
            acc[1] += __builtin_amdgcn_cvt_pk_f32_fp8(u.x, true);
            acc[2] += __builtin_amdgcn_cvt_pk_f32_fp8(u.y, false);
            acc[3] += __builtin_amdgcn_cvt_pk_f32_fp8(u.y, true);
        }
    }
    uint4 o;
    o.x = pk_bf16(acc[0].x, acc[0].y);
    o.y = pk_bf16(acc[1].x, acc[1].y);
    o.z = pk_bf16(acc[2].x, acc[2].y);
    o.w = pk_bf16(acc[3].x, acc[3].y);
    *(uint4*)(Ab + (size_t)node * D + li * 8) = o;
}

// ---------------- fused combine (MFMA), weights staged in LDS ----------------
// O8 != nullptr: additionally emit output rows as fp8 (for next layer's gather)
__global__ __launch_bounds__(256) void k_combine(
    const unsigned short* Xb, const unsigned short* __restrict__ Ab,
    const unsigned short* __restrict__ Wct,
    const unsigned short* __restrict__ Wlt, const float* __restrict__ bl,
    const unsigned short* __restrict__ Wgt, const float* __restrict__ bg,
    const float* __restrict__ ID,
    unsigned short* Ob, float* Of, unsigned char* O8, int N)
{
    __shared__ unsigned short Wc_s[64 * WS], Wl_s[64 * WS], Wg_s[64 * WS];
    __shared__ unsigned short tl[4][16][72];
    int lane = threadIdx.x & 63, w = threadIdx.x >> 6;
    int cl = lane & 15, g = lane >> 4;
    int ntiles = (N + 63) / 64;

    for (int i = threadIdx.x; i < 512; i += 256) {
        int r = i >> 3, c8 = (i & 7) << 3;
        *(uint4*)(Wc_s + r * WS + c8) = *(const uint4*)(Wct + r * 64 + c8);
        *(uint4*)(Wl_s + r * WS + c8) = *(const uint4*)(Wlt + r * 64 + c8);
        *(uint4*)(Wg_s + r * WS + c8) = *(const uint4*)(Wgt + r * 64 + c8);
    }
    float blv[4], bgv[4];
#pragma unroll
    for (int nt = 0; nt < 4; ++nt) {
        blv[nt] = bl[nt * 16 + cl];
        bgv[nt] = bg[nt * 16 + cl];
    }
    __syncthreads();

    for (int tb = blockIdx.x; tb < ntiles; tb += gridDim.x) {
        int node0 = tb * 64 + w * 16;
        bool active = node0 < N;
        f32x4 accL[4], accG[4];
        if (active) {
            const bf16x8* xr = (const bf16x8*)(Xb + (size_t)(node0 + cl) * D + g * 8);
            const bf16x8* ar = (const bf16x8*)(Ab + (size_t)(node0 + cl) * D + g * 8);
            bf16x8 xf0 = xr[0], xf1 = xr[4];
            bf16x8 af0 = ar[0], af1 = ar[4];
            f32x4 accC[4];
#pragma unroll
            for (int nt = 0; nt < 4; ++nt) {
                int wo = (nt * 16 + cl) * WS + g * 8;
                f32x4 z = (f32x4){0.f, 0.f, 0.f, 0.f};
                accL[nt] = __builtin_amdgcn_mfma_f32_16x16x32_bf16(xf1,
                            *(const bf16x8*)(Wl_s + wo + 32),
                            __builtin_amdgcn_mfma_f32_16x16x32_bf16(xf0,
                                *(const bf16x8*)(Wl_s + wo), z, 0, 0, 0), 0, 0, 0);
                accC[nt] = __builtin_amdgcn_mfma_f32_16x16x32_bf16(af1,
                            *(const bf16x8*)(Wc_s + wo + 32),
                            __builtin_amdgcn_mfma_f32_16x16x32_bf16(af0,
                                *(const bf16x8*)(Wc_s + wo), z, 0, 0, 0), 0, 0, 0);
            }
#pragma unroll
            for (int nt = 0; nt < 4; ++nt)
#pragma unroll
                for (int i = 0; i < 4; ++i)
                    tl[w][g * 4 + i][nt * 16 + cl] = f2bf(leaky(accC[nt][i]));
        }
        __syncthreads();
        if (active) {
            const bf16x8* tr = (const bf16x8*)&tl[w][cl][g * 8];
            bf16x8 tf0 = tr[0], tf1 = tr[4];
#pragma unroll
            for (int nt = 0; nt < 4; ++nt) {
                int wo = (nt * 16 + cl) * WS + g * 8;
                f32x4 z = (f32x4){0.f, 0.f, 0.f, 0.f};
                accG[nt] = __builtin_amdgcn_mfma_f32_16x16x32_bf16(tf1,
                            *(const bf16x8*)(Wg_s + wo + 32),
                            __builtin_amdgcn_mfma_f32_16x16x32_bf16(tf0,
                                *(const bf16x8*)(Wg_s + wo), z, 0, 0, 0), 0, 0, 0);
            }
#pragma unroll
            for (int nt = 0; nt < 4; ++nt) {
                int col = nt * 16 + cl;
#pragma unroll
                for (int i = 0; i < 4; ++i) {
                    size_t row = (size_t)(node0 + g * 4 + i);
                    float xh = leaky(accL[nt][i] + blv[nt]) + ID[row * D + col];
                    float o = leaky(accG[nt][i] + bgv[nt] + xh);
                    if (Ob) Ob[row * D + col] = f2bf(o);
                    else    Of[row * D + col] = o;
                    if (O8) {
                        int p8 = __builtin_amdgcn_cvt_pk_fp8_f32(o, o, 0, false);
                        O8[row * D + col] = (unsigned char)(p8 & 0xFF);
                    }
                }
            }
        }
        __syncthreads();
    }
}

extern "C" void kernel_launch(void* const* d_in, const int* in_sizes, int n_in,
                              void* d_out, int out_size, void* d_ws, size_t ws_size,
                              hipStream_t stream)
{
    const float* features = (const float*)d_in[0];
    const float* id_emb   = (const float*)d_in[1];
    const int*   eidx     = (const int*)d_in[2];
    const float* W_mlp    = (const float*)d_in[3];
    const float* b_mlp    = (const float*)d_in[4];
    const float* Wc1 = (const float*)d_in[5];
    const float* Wl1 = (const float*)d_in[6];
    const float* bl1 = (const float*)d_in[7];
    const float* Wg1 = (const float*)d_in[8];
    const float* bg1 = (const float*)d_in[9];
    const float* Wc2 = (const float*)d_in[10];
    const float* Wl2 = (const float*)d_in[11];
    const float* bl2 = (const float*)d_in[12];
    const float* Wg2 = (const float*)d_in[13];
    const float* bg2 = (const float*)d_in[14];

    int N = in_sizes[0] / D_FEAT;
    int E = in_sizes[2] / 2;
    const int* esrc = eidx;
    const int* edst = eidx + E;
    int nbk = (N + BW - 1) >> BSH;               // 782 for N=100000

    char* wp = (char*)d_ws;
    unsigned short* Xb = (unsigned short*)wp;              wp += (size_t)N * D * 2;
    unsigned short* Ab = (unsigned short*)wp;              wp += (size_t)N * D * 2;
    int* srcs = (int*)wp;                                  wp += (size_t)nbk * CAP * 4;
    int2* rng = (int2*)wp;                                 wp += (size_t)N * 8;
    int* gcur = (int*)wp;                                  wp += 1024 * 4;
    unsigned short* wt = (unsigned short*)wp;              wp += (8192 + 6 * 4096) * 2;
    unsigned char* Xf8 = (unsigned char*)wp;               wp += (size_t)N * D;

    unsigned short* Wmt  = wt;
    unsigned short* Wct1 = wt + 8192;
    unsigned short* Wlt1 = Wct1 + 4096;
    unsigned short* Wgt1 = Wlt1 + 4096;
    unsigned short* Wct2 = Wgt1 + 4096;
    unsigned short* Wlt2 = Wct2 + 4096;
    unsigned short* Wgt2 = Wlt2 + 4096;

    // pairs scratch lives in d_out (25.6 MB >= nbk*CAP*4 = 8.0 MB); fully dead
    // before the final combine writes d_out.
    unsigned* pairs = (unsigned*)d_out;

    dim3 blk(256);
    int egrid = (E + 4095) / 4096;               // 391 partition blocks
    int cgrid = 782;                             // ~3 blocks/CU, 2 tiles each
    int ggrid = (N + 31) / 32;                   // 8 nodes per wave

    P7 p7;
    p7.w[0] = W_mlp; p7.w[1] = Wc1; p7.w[2] = Wl1; p7.w[3] = Wg1;
    p7.w[4] = Wc2; p7.w[5] = Wl2; p7.w[6] = Wg2;

    // weight transpose + gcur init (one dispatch)
    k_prep<<<8, blk, 0, stream>>>(p7, wt, gcur, nbk);

    // edge partition || MLP (independent -> one dispatch)
    k_partmlp<<<egrid + 512, blk, 0, stream>>>(esrc, edst, gcur, pairs, E, egrid,
                                               features, Wmt, b_mlp, Xb, Xf8, N);

    // per-bucket sort -> per-node CSR
    k_sort<<<nbk, blk, 0, stream>>>(pairs, gcur, rng, srcs, N);

    // layer 1: fp8 gather of x0; combine writes x1 bf16 (in-place) + x1 fp8
    k_gather8<<<ggrid, blk, 0, stream>>>(rng, srcs, Xf8, Ab, N);
    k_combine<<<cgrid, blk, 0, stream>>>(Xb, Ab, Wct1, Wlt1, bl1, Wgt1, bg1, id_emb,
                                         Xb, (float*)nullptr, Xf8, N);

    // layer 2: fp8 gather of x1 (err budget: e4m3 on N(0,1) -> ~0.03 output delta)
    k_gather8<<<ggrid, blk, 0, stream>>>(rng, srcs, Xf8, Ab, N);
    k_combine<<<cgrid, blk, 0, stream>>>(Xb, Ab, Wct2, Wlt2, bl2, Wgt2, bg2, id_emb,
                                         (unsigned short*)nullptr, (float*)d_out,
                                         (unsigned char*)nullptr, N);
}